// Round 6
// baseline (608.431 us; speedup 1.0000x reference)
//
#include <hip/hip_runtime.h>

// Spiking self-attention block (spikformer SSA), MI355X fp32 implementation.
// T=4 B=32 C=384 H=W=14 (N=196), heads=8, d=48.
//
// Exactness: LIF spikes are EXACTLY 0/1; attention is exact integer math
// (order-independent). Conv GEMM: single fp32 accumulator per output,
// ascending K, fmaf per step (matched XLA bit-for-bit rounds 1-5).
//
// R6: GEMM rebuilt around wave-uniform A ("A-broadcast"): each wave owns 8
// co rows -> A fragment is 2 broadcast ds_read_b128 (16 B, conflict-free);
// lanes spread over 512 cols. LDS bytes/MAC drop 1.0 -> ~0.5, moving the
// kernel from LDS-bound (~70% VALU, R5 measured) to VALU-bound.
// Block 768 thr = 12 waves, co-tile 96, col-tile 512 (25088 = 49*512).
// fused_attn Phase A chunked 4 tasks (16 loads in flight) to cut the
// serialized ~900-cyc HBM round-trips 4x.

#define T_ 4
#define B_ 32
#define C_ 384
#define N_ 196
#define NH_ 8
#define D_ 48
#define TB_ (T_ * B_)                 // 128
#define CN_ ((size_t)C_ * N_)         // 75264
#define BCN4_ (B_ * C_ * (N_ / 4))    // 602112 float4 units per (g,t)
#define TBCN_ ((size_t)T_ * B_ * C_ * N_)  // 9,633,792 floats
typedef unsigned long long u64;

// ---------------------------------------------------------------------------
// GEMM: Y[g][tb][co][n] = sum_c Wg[co][c] * X[tb][c][n]
// Flattened cols j = tb*196 + n; 25088 = 49 tiles of 512.
// Block: 768 thr = 12 waves; wave w -> co rows co0+w*8..+7 (A broadcast),
// lanes -> col quads lane*4 and 256+lane*4. acc[8][8]/lane, ~0.5 B LDS/MAC.
// grid: x = col-tile (49), y = co-tile (4 x 96), z = g
// ---------------------------------------------------------------------------
__global__ __launch_bounds__(768, 3) void gemm_bw(
    const float* __restrict__ X, const float* __restrict__ W0,
    const float* __restrict__ W1, const float* __restrict__ W2,
    float* __restrict__ P)
{
  const int g = blockIdx.z;
  const float* __restrict__ W = (g == 0) ? W0 : (g == 1) ? W1 : W2;
  const int co0 = blockIdx.y * 96;
  const int j0 = blockIdx.x * 512;
  __shared__ float Bs[16][512];     // 32 KB
  __shared__ float As[16][100];     // 6.25 KB (pad 96->100: write conflicts 2-way)
  const int tid = threadIdx.x;
  const int wave = tid >> 6, lane = tid & 63;
  const int w8 = wave * 8;
  const int lane4 = lane * 4;

  // A-staging task (threads 0..383): W[co0+r][c0+q*4..+3] -> As[q*4+j][r]
  const int ar = tid >> 2, aq = tid & 3;
  // B-staging: units u in [0,2048): k=u>>7, colq=(u&127)*4 (quad tb-safe)
  float acc[8][8] = {};

  for (int c0 = 0; c0 < C_; c0 += 16) {
    if (tid < 384) {
      const float4 w4 = *(const float4*)(W + (size_t)(co0 + ar) * C_ + c0 + aq * 4);
      As[aq * 4 + 0][ar] = w4.x; As[aq * 4 + 1][ar] = w4.y;
      As[aq * 4 + 2][ar] = w4.z; As[aq * 4 + 3][ar] = w4.w;
    }
    for (int u = tid; u < 2048; u += 768) {
      const int k = u >> 7;
      const int colq = (u & 127) * 4;
      const int j = j0 + colq;
      const int tb = j / N_;
      *(float4*)&Bs[k][colq] =
          *(const float4*)(X + (size_t)tb * CN_ + (size_t)(c0 + k) * N_ + (j - tb * N_));
    }
    __syncthreads();
#pragma unroll
    for (int k = 0; k < 16; ++k) {
      float a[8], b[8];
      *(float4*)&a[0] = *(const float4*)&As[k][w8];        // broadcast
      *(float4*)&a[4] = *(const float4*)&As[k][w8 + 4];    // broadcast
      *(float4*)&b[0] = *(const float4*)&Bs[k][lane4];
      *(float4*)&b[4] = *(const float4*)&Bs[k][256 + lane4];
#pragma unroll
      for (int i = 0; i < 8; ++i)
#pragma unroll
        for (int j = 0; j < 8; ++j)
          acc[i][j] = fmaf(a[i], b[j], acc[i][j]);
    }
    __syncthreads();
  }
  // Epilogue: two float4 stores per co row (col quads never straddle tb).
  {
    const int jA = j0 + lane4;
    const int jB = j0 + 256 + lane4;
    const int tbA = jA / N_, tbB = jB / N_;
    float* pA = P + (size_t)(g * TB_ + tbA) * CN_ + (jA - tbA * N_);
    float* pB = P + (size_t)(g * TB_ + tbB) * CN_ + (jB - tbB * N_);
#pragma unroll
    for (int i = 0; i < 8; ++i) {
      const size_t ro = (size_t)(co0 + w8 + i) * N_;
      *(float4*)&pA[ro] = make_float4(acc[i][0], acc[i][1], acc[i][2], acc[i][3]);
      *(float4*)&pB[ro] = make_float4(acc[i][4], acc[i][5], acc[i][6], acc[i][7]);
    }
  }
}

// ---------------------------------------------------------------------------
// Multi-step LIF over t with folded BN (final conv only).
// ---------------------------------------------------------------------------
__global__ __launch_bounds__(256) void lif4(
    const float* __restrict__ In, float* __restrict__ Out,
    const float* __restrict__ s0, const float* __restrict__ b0, float vth)
{
  const long u = (long)blockIdx.x * 256 + threadIdx.x;
  if (u >= BCN4_) return;
  const long r = u;
  const int c = (int)((r / (N_ / 4)) % C_);
  const bool has_bn = (s0 != nullptr);
  const float sc = has_bn ? s0[c] : 1.0f;
  const float bi = has_bn ? b0[c] : 0.0f;
  const float4* In4 = (const float4*)In;
  float4* Out4 = (float4*)Out;
  float v[4] = {0.f, 0.f, 0.f, 0.f};
#pragma unroll
  for (int t = 0; t < T_; ++t) {
    const long idx = (long)t * BCN4_ + r;
    const float4 y4 = In4[idx];
    float y[4] = {y4.x, y4.y, y4.z, y4.w};
    float o[4];
#pragma unroll
    for (int e = 0; e < 4; ++e) {
      const float yb = has_bn ? __fadd_rn(__fmul_rn(y[e], sc), bi) : y[e];
      v[e] = __fadd_rn(v[e], __fmul_rn(__fsub_rn(yb, v[e]), 0.5f));
      const bool fire = (v[e] >= vth);
      o[e] = fire ? 1.0f : 0.0f;
      v[e] = fire ? 0.0f : v[e];
    }
    Out4[idx] = make_float4(o[0], o[1], o[2], o[3]);
  }
}

// ---------------------------------------------------------------------------
// Fused qkv-LIF + attention + attn-LIF. One block per (h, b), 1024 threads.
//  A: LIF -> bitmasks msk[g][t][j][w]; tasks chunked x4 so 16 global loads
//     are in flight per wave (was 4 -> latency-serialized).
//  A2a: qT[t][n] (q bits over j); A2b: Gp[t][p][d] bit-planes of
//       G[j][d] = popcount_m(k_j & v_d), via ballot with lanes=j.
//  B: per t, no barriers: out = sum_p 2^p popcount(qT & Gp[p][d]); attn-LIF.
// ---------------------------------------------------------------------------
__global__ __launch_bounds__(1024) void fused_attn(
    const float* __restrict__ P, float* __restrict__ O,
    const float* __restrict__ sq, const float* __restrict__ bq,
    const float* __restrict__ sk, const float* __restrict__ bk,
    const float* __restrict__ sv, const float* __restrict__ bv)
{
  const int h = blockIdx.x;   // 8
  const int b = blockIdx.y;   // 32
  __shared__ u64 msk[3][T_][D_][4];   // 18432 B
  __shared__ u64 qT[T_][208];         // 6656 B
  __shared__ u64 Gp[T_][8][D_];       // 12288 B
  const int tid = threadIdx.x;
  const int wave = tid >> 6, lane = tid & 63;

  // ---- Phase A: conv-LIF -> spike bitmasks; 4-task chunks (16 loads) ----
  for (int base = wave; base < 3 * D_ * 4; base += 64) {  // 9 chunks of 4
    float y[4][T_];
    float sc[4], bi[4];
    int gj[4], jj[4], ww[4];
    bool act[4];
#pragma unroll
    for (int q = 0; q < 4; ++q) {
      const int task = base + q * 16;
      const int g = task / (D_ * 4);
      const int rem = task - g * (D_ * 4);
      const int j = rem >> 2, w = rem & 3;
      gj[q] = g; jj[q] = j; ww[q] = w;
      const int m = w * 64 + lane;
      act[q] = (m < N_);
      const int mc = act[q] ? m : (N_ - 1);
      const int c = h * D_ + j;
      sc[q] = (g == 0 ? sq : g == 1 ? sk : sv)[c];
      bi[q] = (g == 0 ? bq : g == 1 ? bk : bv)[c];
      const float* bp_ = P + (size_t)g * TB_ * CN_ + (size_t)b * CN_
                           + (size_t)c * N_ + mc;
#pragma unroll
      for (int t = 0; t < T_; ++t) y[q][t] = bp_[(size_t)t * B_ * CN_];
    }
#pragma unroll
    for (int q = 0; q < 4; ++q) {
      float v = 0.f;
#pragma unroll
      for (int t = 0; t < T_; ++t) {
        const float yb = __fadd_rn(__fmul_rn(y[q][t], sc[q]), bi[q]);
        v = __fadd_rn(v, __fmul_rn(__fsub_rn(yb, v), 0.5f));
        const bool fire = (v >= 1.0f);
        if (fire) v = 0.f;
        const u64 bl = __ballot(fire && act[q]);
        if (lane == 0) msk[gj[q]][t][jj[q]][ww[q]] = bl;
      }
    }
  }
  __syncthreads();

  // ---- Phase A2a: transpose q masks -> qT[t][n] (bits over j) ----
  {
    const int t = wave >> 2, w = wave & 3;
    const int n = w * 64 + lane;
    u64 qr = 0ull;
#pragma unroll 8
    for (int j = 0; j < D_; ++j)
      qr |= ((msk[0][t][j][w] >> lane) & 1ull) << j;
    if (n < N_) qT[t][n] = qr;
  }
  // ---- Phase A2b: G bit-planes via ballot (wave-task = (t,d), lanes=j) ----
  for (int task = wave; task < T_ * D_; task += 16) {
    const int t = task / D_, d = task - (task / D_) * D_;
    const bool ja = (lane < D_);
    const int j = ja ? lane : (D_ - 1);
    const u64* kj = msk[1][t][j];
    const u64* vd = msk[2][t][d];
    const int gi = __popcll(kj[0] & vd[0]) + __popcll(kj[1] & vd[1]) +
                   __popcll(kj[2] & vd[2]) + __popcll(kj[3] & vd[3]);
#pragma unroll
    for (int p = 0; p < 8; ++p) {
      const u64 bl = __ballot(ja && ((gi >> p) & 1));
      if (lane == 0) Gp[t][p][d] = bl;
    }
  }
  __syncthreads();

  // ---- Phase B: apply + attn-LIF, no barriers across t ----
  const int u = tid;
  if (u < 4 * N_) {
    const int dq = u / N_;
    const int n = u - dq * N_;
    const int d0 = dq * 12;
    float vmem[12];
#pragma unroll
    for (int i = 0; i < 12; ++i) vmem[i] = 0.f;
    for (int t = 0; t < T_; ++t) {
      const u64 qr = qT[t][n];
      float* ob = O + ((size_t)(t * B_ + b) * C_ + h * D_ + d0) * N_ + n;
#pragma unroll
      for (int i = 0; i < 12; ++i) {
        int acc = 0;
#pragma unroll
        for (int p = 0; p < 8; ++p)
          acc += __popcll(qr & Gp[t][p][d0 + i]) << p;
        const float y = __int2float_rn(acc) * 0.125f;  // exact
        vmem[i] = __fadd_rn(vmem[i], __fmul_rn(__fsub_rn(y, vmem[i]), 0.5f));
        const bool fire = (vmem[i] >= 0.5f);
        ob[(size_t)i * N_] = fire ? 1.0f : 0.0f;
        if (fire) vmem[i] = 0.f;
      }
    }
  }
}

// ---------------------------------------------------------------------------
extern "C" void kernel_launch(void* const* d_in, const int* in_sizes, int n_in,
                              void* d_out, int out_size, void* d_ws, size_t ws_size,
                              hipStream_t stream) {
  const float* x  = (const float*)d_in[0];
  const float* wq = (const float*)d_in[1];
  const float* sq = (const float*)d_in[2];
  const float* bq = (const float*)d_in[3];
  const float* wk = (const float*)d_in[4];
  const float* sk = (const float*)d_in[5];
  const float* bk = (const float*)d_in[6];
  const float* wv = (const float*)d_in[7];
  const float* sv = (const float*)d_in[8];
  const float* bv = (const float*)d_in[9];
  const float* wp = (const float*)d_in[10];
  const float* sp = (const float*)d_in[11];
  const float* bp = (const float*)d_in[12];
  float* out = (float*)d_out;

  float* P = (float*)d_ws;          // 3*TBCN qkv preacts
  float* O = P + 3 * TBCN_;         // TBCN attn spikes
  float* P2 = P;                    // final conv preact reuses q region

  gemm_bw<<<dim3(49, 4, 3), 768, 0, stream>>>(x, wq, wk, wv, P);
  fused_attn<<<dim3(NH_, B_), 1024, 0, stream>>>(P, O, sq, bq, sk, bk, sv, bv);
  gemm_bw<<<dim3(49, 4, 1), 768, 0, stream>>>(O, wp, wp, wp, P2);
  lif4<<<dim3((BCN4_ + 255) / 256), 256, 0, stream>>>(P2, out, sp, bp, 1.0f);
}

// Round 7
// 575.795 us; speedup vs baseline: 1.0567x; 1.0567x over previous
//
#include <hip/hip_runtime.h>

// Spiking self-attention block (spikformer SSA), MI355X fp32 implementation.
// T=4 B=32 C=384 H=W=14 (N=196), heads=8, d=48.
//
// Exactness: LIF spikes are EXACTLY 0/1; attention is exact integer math
// (order-independent). Conv GEMM: single fp32 accumulator per output,
// ascending K, fmaf per step (matched XLA bit-for-bit rounds 1-6).
//
// R7: (a) GEMM rebuilt: 512 thr, 128co x 256col; wave owns 16 co rows so the
// A-fragment is 4 same-address-broadcast ds_read_b128 (free) -> ~0.27 B
// LDS/MAC (R3 was 1.0 B/MAC = LDS-bound at 85 B/cyc -> 70% VALU cap).
// __launch_bounds__ SINGLE-ARG: the second arg produced a 64-VGPR cap and
// full accumulator spill twice ((256,4) R2, (768,3) R6). Never again.
// (b) fused_attn split into k_mask (BW-bound ballot kernel, 9216 blocks) +
// k_attn (per (h,b) bit-plane attention) for rocprof visibility + 8x more
// parallelism in the HBM-bound phase.

#define T_ 4
#define B_ 32
#define C_ 384
#define N_ 196
#define NH_ 8
#define D_ 48
#define TB_ (T_ * B_)                 // 128
#define CN_ ((size_t)C_ * N_)         // 75264
#define BCN4_ (B_ * C_ * (N_ / 4))    // 602112 float4 units per (g,t)
#define TBCN_ ((size_t)T_ * B_ * C_ * N_)  // 9,633,792 floats
typedef unsigned long long u64;

// ---------------------------------------------------------------------------
// GEMM: Y[g][tb][co][n] = sum_c Wg[co][c] * X[tb][c][n]
// Flattened cols j = tb*196 + n; 25088 = 98 tiles of 256.
// Block: 512 thr = 8 waves. Wave w owns co rows co0+w*16..+15 (A broadcast:
// all 64 lanes read the same As address -> free). Lane owns cols lane*4..+3.
// acc[16][4] per thread. grid: x = col-tile (98), y = co-tile (3), z = g.
// ---------------------------------------------------------------------------
__global__ __launch_bounds__(512) void gemm_f32(
    const float* __restrict__ X, const float* __restrict__ W0,
    const float* __restrict__ W1, const float* __restrict__ W2,
    float* __restrict__ P)
{
  const int g = blockIdx.z;
  const float* __restrict__ W = (g == 0) ? W0 : (g == 1) ? W1 : W2;
  const int co0 = blockIdx.y * 128;
  const int j0 = blockIdx.x * 256;
  __shared__ float As[16][132];   // 8448 B (pad 128->132)
  __shared__ float Bs[16][256];   // 16384 B
  const int tid = threadIdx.x;
  const int wave = tid >> 6, lane = tid & 63;
  const int w16 = wave * 16;
  const int lane4 = lane * 4;

  // A staging: thread -> W[co0+ar][c0+aq*4..+3] scattered to As[aq4+i][ar]
  const int ar = tid >> 2, aq4 = (tid & 3) * 4;
  const float* wrow = W + (size_t)(co0 + ar) * C_ + aq4;
  // B staging: thread -> col quad lane4, k rows wave and wave+8 (hoisted).
  const int bj = j0 + lane4;
  const int btb = bj / N_;                      // quad never straddles tb
  const float* xcol = X + (size_t)btb * CN_ + (bj - btb * N_);
  // Epilogue base (same col quad).
  float* pbase = P + (size_t)(g * TB_ + btb) * CN_ + (bj - btb * N_);

  float acc[16][4] = {};
  for (int c0 = 0; c0 < C_; c0 += 16) {
    const float4 w4 = *(const float4*)(wrow + c0);
    As[aq4 + 0][ar] = w4.x; As[aq4 + 1][ar] = w4.y;
    As[aq4 + 2][ar] = w4.z; As[aq4 + 3][ar] = w4.w;
    *(float4*)&Bs[wave][lane4] =
        *(const float4*)(xcol + (size_t)(c0 + wave) * N_);
    *(float4*)&Bs[wave + 8][lane4] =
        *(const float4*)(xcol + (size_t)(c0 + wave + 8) * N_);
    __syncthreads();
#pragma unroll
    for (int k = 0; k < 16; ++k) {
      float b[4], a[16];
      *(float4*)&b[0] = *(const float4*)&Bs[k][lane4];
#pragma unroll
      for (int q = 0; q < 4; ++q)
        *(float4*)&a[q * 4] = *(const float4*)&As[k][w16 + q * 4];  // broadcast
#pragma unroll
      for (int i = 0; i < 16; ++i)
#pragma unroll
        for (int jj = 0; jj < 4; ++jj)
          acc[i][jj] = fmaf(a[i], b[jj], acc[i][jj]);
    }
    __syncthreads();
  }
#pragma unroll
  for (int i = 0; i < 16; ++i)
    *(float4*)&pbase[(size_t)(co0 + w16 + i) * N_] =
        make_float4(acc[i][0], acc[i][1], acc[i][2], acc[i][3]);
}

// ---------------------------------------------------------------------------
// Multi-step LIF over t with folded BN (final conv only).
// ---------------------------------------------------------------------------
__global__ __launch_bounds__(256) void lif4(
    const float* __restrict__ In, float* __restrict__ Out,
    const float* __restrict__ s0, const float* __restrict__ b0, float vth)
{
  const long u = (long)blockIdx.x * 256 + threadIdx.x;
  if (u >= BCN4_) return;
  const long r = u;
  const int c = (int)((r / (N_ / 4)) % C_);
  const bool has_bn = (s0 != nullptr);
  const float sc = has_bn ? s0[c] : 1.0f;
  const float bi = has_bn ? b0[c] : 0.0f;
  const float4* In4 = (const float4*)In;
  float4* Out4 = (float4*)Out;
  float v[4] = {0.f, 0.f, 0.f, 0.f};
#pragma unroll
  for (int t = 0; t < T_; ++t) {
    const long idx = (long)t * BCN4_ + r;
    const float4 y4 = In4[idx];
    float y[4] = {y4.x, y4.y, y4.z, y4.w};
    float o[4];
#pragma unroll
    for (int e = 0; e < 4; ++e) {
      const float yb = has_bn ? __fadd_rn(__fmul_rn(y[e], sc), bi) : y[e];
      v[e] = __fadd_rn(v[e], __fmul_rn(__fsub_rn(yb, v[e]), 0.5f));
      const bool fire = (v[e] >= vth);
      o[e] = fire ? 1.0f : 0.0f;
      v[e] = fire ? 0.0f : v[e];
    }
    Out4[idx] = make_float4(o[0], o[1], o[2], o[3]);
  }
}

// ---------------------------------------------------------------------------
// k_mask: conv-LIF -> spike bitmasks. Wave-task = (g,h,b,j): 16 loads in
// flight (4 words x 4 t), LIF recurrence, 16 ballots, lane0 stores 16 u64.
// MSK layout: [(h*32+b)][g][t][j][w]  (2304 u64 per (h,b)).
// ---------------------------------------------------------------------------
__global__ __launch_bounds__(256) void k_mask(
    const float* __restrict__ P, u64* __restrict__ MSK,
    const float* __restrict__ sq, const float* __restrict__ bq,
    const float* __restrict__ sk, const float* __restrict__ bk,
    const float* __restrict__ sv, const float* __restrict__ bv)
{
  const int wave = threadIdx.x >> 6, lane = threadIdx.x & 63;
  const int task = blockIdx.x * 4 + wave;      // 0..36863
  const int j = task % D_;
  int r = task / D_;
  const int b = r & 31; r >>= 5;
  const int h = r & 7;  r >>= 3;
  const int g = r;                              // 0..2
  const int c = h * D_ + j;
  const float sc = (g == 0 ? sq : g == 1 ? sk : sv)[c];
  const float bi = (g == 0 ? bq : g == 1 ? bk : bv)[c];
  const float* base = P + (size_t)g * TB_ * CN_ + (size_t)b * CN_ + (size_t)c * N_;

  float y[4][T_];
  bool act[4];
#pragma unroll
  for (int w = 0; w < 4; ++w) {
    const int m = w * 64 + lane;
    act[w] = (m < N_);
    const int mc = act[w] ? m : (N_ - 1);
#pragma unroll
    for (int t = 0; t < T_; ++t)
      y[w][t] = base[(size_t)t * B_ * CN_ + mc];   // 16 independent loads
  }
  u64* mb = MSK + ((size_t)(h * 32 + b) * 3 + g) * (T_ * D_ * 4) + j * 4;
  float v[4] = {0.f, 0.f, 0.f, 0.f};
#pragma unroll
  for (int t = 0; t < T_; ++t) {
#pragma unroll
    for (int w = 0; w < 4; ++w) {
      const float yb = __fadd_rn(__fmul_rn(y[w][t], sc), bi);
      v[w] = __fadd_rn(v[w], __fmul_rn(__fsub_rn(yb, v[w]), 0.5f));
      const bool fire = (v[w] >= 1.0f);
      if (fire) v[w] = 0.f;
      const u64 bl = __ballot(fire && act[w]);
      if (lane == 0) mb[(size_t)t * (D_ * 4) + w] = bl;
    }
  }
}

// ---------------------------------------------------------------------------
// k_attn: per (h,b): load 18 KB of masks to LDS, build qT + G bit-planes,
// apply out = sum_p 2^p popcount(qT & Gp[p][d]), attn-LIF, write spikes.
// ---------------------------------------------------------------------------
__global__ __launch_bounds__(1024) void k_attn(
    const u64* __restrict__ MSK, float* __restrict__ O)
{
  const int h = blockIdx.x;   // 8
  const int b = blockIdx.y;   // 32
  __shared__ u64 msk[3][T_][D_][4];   // 18432 B
  __shared__ u64 qT[T_][208];         // 6656 B
  __shared__ u64 Gp[T_][8][D_];       // 12288 B
  const int tid = threadIdx.x;
  const int wave = tid >> 6, lane = tid & 63;

  {
    const u64* ms = MSK + (size_t)(h * 32 + b) * 2304;
    u64* mf = &msk[0][0][0][0];
    for (int off = tid; off < 2304; off += 1024) mf[off] = ms[off];
  }
  __syncthreads();

  // qT[t][n] = q bits over j
  {
    const int t = wave >> 2, w = wave & 3;
    const int n = w * 64 + lane;
    u64 qr = 0ull;
#pragma unroll 8
    for (int j = 0; j < D_; ++j)
      qr |= ((msk[0][t][j][w] >> lane) & 1ull) << j;
    if (n < N_) qT[t][n] = qr;
  }
  // Gp[t][p][d]: bit-planes of G[j][d] = popcount_m(k_j & v_d), lanes=j
  for (int task = wave; task < T_ * D_; task += 16) {
    const int t = task / D_, d = task - (task / D_) * D_;
    const bool ja = (lane < D_);
    const int j = ja ? lane : (D_ - 1);
    const u64* kj = msk[1][t][j];
    const u64* vd = msk[2][t][d];
    const int gi = __popcll(kj[0] & vd[0]) + __popcll(kj[1] & vd[1]) +
                   __popcll(kj[2] & vd[2]) + __popcll(kj[3] & vd[3]);
#pragma unroll
    for (int p = 0; p < 8; ++p) {
      const u64 bl = __ballot(ja && ((gi >> p) & 1));
      if (lane == 0) Gp[t][p][d] = bl;
    }
  }
  __syncthreads();

  const int u = tid;
  if (u < 4 * N_) {
    const int dq = u / N_;
    const int n = u - dq * N_;
    const int d0 = dq * 12;
    float vmem[12];
#pragma unroll
    for (int i = 0; i < 12; ++i) vmem[i] = 0.f;
    for (int t = 0; t < T_; ++t) {
      const u64 qr = qT[t][n];
      float* ob = O + ((size_t)(t * B_ + b) * C_ + h * D_ + d0) * N_ + n;
#pragma unroll
      for (int i = 0; i < 12; ++i) {
        int acc = 0;
#pragma unroll
        for (int p = 0; p < 8; ++p)
          acc += __popcll(qr & Gp[t][p][d0 + i]) << p;
        const float y = __int2float_rn(acc) * 0.125f;  // exact
        vmem[i] = __fadd_rn(vmem[i], __fmul_rn(__fsub_rn(y, vmem[i]), 0.5f));
        const bool fire = (vmem[i] >= 0.5f);
        ob[(size_t)i * N_] = fire ? 1.0f : 0.0f;
        if (fire) vmem[i] = 0.f;
      }
    }
  }
}

// ---------------------------------------------------------------------------
extern "C" void kernel_launch(void* const* d_in, const int* in_sizes, int n_in,
                              void* d_out, int out_size, void* d_ws, size_t ws_size,
                              hipStream_t stream) {
  const float* x  = (const float*)d_in[0];
  const float* wq = (const float*)d_in[1];
  const float* sq = (const float*)d_in[2];
  const float* bq = (const float*)d_in[3];
  const float* wk = (const float*)d_in[4];
  const float* sk = (const float*)d_in[5];
  const float* bk = (const float*)d_in[6];
  const float* wv = (const float*)d_in[7];
  const float* sv = (const float*)d_in[8];
  const float* bv = (const float*)d_in[9];
  const float* wp = (const float*)d_in[10];
  const float* sp = (const float*)d_in[11];
  const float* bp = (const float*)d_in[12];
  float* out = (float*)d_out;

  float* P = (float*)d_ws;              // 3*TBCN qkv preacts
  float* O = P + 3 * TBCN_;             // TBCN attn spikes
  u64* MSK = (u64*)(P + 4 * TBCN_);     // 256 * 2304 u64 = 4.7 MB
  float* P2 = P;                        // final conv preact reuses q region

  gemm_f32<<<dim3(98, 3, 3), 512, 0, stream>>>(x, wq, wk, wv, P);
  k_mask<<<dim3(9216), 256, 0, stream>>>(P, MSK, sq, bq, sk, bk, sv, bv);
  k_attn<<<dim3(NH_, B_), 1024, 0, stream>>>(MSK, O);
  gemm_f32<<<dim3(98, 3, 1), 512, 0, stream>>>(O, wp, wp, wp, P2);
  lif4<<<dim3((BCN4_ + 255) / 256), 256, 0, stream>>>(P2, out, sp, bp, 1.0f);
}

// Round 8
// 505.886 us; speedup vs baseline: 1.2027x; 1.1382x over previous
//
#include <hip/hip_runtime.h>

// Spiking self-attention block (spikformer SSA), MI355X fp32 implementation.
// T=4 B=32 C=384 H=W=14 (N=196), heads=8, d=48.
//
// Exactness: LIF spikes are EXACTLY 0/1; attention is exact integer math
// (order-independent). Conv GEMM: single fp32 accumulator per output,
// ascending K, fmaf per step (matched XLA bit-for-bit rounds 1-7). Any
// summation-order change risks LIF spike flips -> MFMA off the table.
//
// R8: GEMM reverted to the R3 config (best measured: 264 us qkv / 88 us wp;
// R6-R7 "improvements" both regressed: (768,3)->VGPR64 spill, 16x4-acc ->
// 59% VALU + 294-block wp grid = 1.15 blk/CU = 2 dispatch rounds).
// Attention stays split: k_mask (BW-bound ballot, 9216 blocks) + k_attn
// (per-(h,b) bit-plane popcount attention), from R7.

#define T_ 4
#define B_ 32
#define C_ 384
#define N_ 196
#define NH_ 8
#define D_ 48
#define TB_ (T_ * B_)                 // 128
#define CN_ ((size_t)C_ * N_)         // 75264
#define BCN4_ (B_ * C_ * (N_ / 4))    // 602112 float4 units per (g,t)
#define TBCN_ ((size_t)T_ * B_ * C_ * N_)  // 9,633,792 floats
typedef unsigned long long u64;

// ---------------------------------------------------------------------------
// GEMM (R3 config): Y[g][tb][co][n] = sum_c Wg[co][c] * X[tb][c][n]
// Cols flattened j = tb*196 + n; 25088 = 196 tiles of 128 (exact).
// Block: 128co x 128col, 256 thr, 8x8/thread in two stride-64 quads.
// grid: x = col-tile (196), y = co-tile (3), z = g
// ---------------------------------------------------------------------------
__global__ __launch_bounds__(256, 2) void gemm_f32(
    const float* __restrict__ X, const float* __restrict__ W0,
    const float* __restrict__ W1, const float* __restrict__ W2,
    float* __restrict__ P)
{
  const int g = blockIdx.z;
  const float* __restrict__ W = (g == 0) ? W0 : (g == 1) ? W1 : W2;
  const int co0 = blockIdx.y * 128;
  const int j0 = blockIdx.x * 128;
  __shared__ float As[16][128];
  __shared__ float Bs[16][128];
  const int tid = threadIdx.x;
  const int tx = tid & 15, ty = tid >> 4;

  const int bcol = (tid & 31) * 4;
  const int bk = tid >> 5;
  const int bj = j0 + bcol;
  const int btb = bj / N_;
  const float* xb = X + (size_t)btb * CN_ + (bj - btb * N_);
  const int arow = tid >> 1;
  const int ac8 = (tid & 1) * 8;

  float acc[8][8] = {};
  for (int c0 = 0; c0 < C_; c0 += 16) {
    const float* wrow = W + (size_t)(co0 + arow) * C_ + c0 + ac8;
    const float4 a0 = *(const float4*)wrow;
    const float4 a1 = *(const float4*)(wrow + 4);
    As[ac8 + 0][arow] = a0.x; As[ac8 + 1][arow] = a0.y;
    As[ac8 + 2][arow] = a0.z; As[ac8 + 3][arow] = a0.w;
    As[ac8 + 4][arow] = a1.x; As[ac8 + 5][arow] = a1.y;
    As[ac8 + 6][arow] = a1.z; As[ac8 + 7][arow] = a1.w;
    *(float4*)&Bs[bk][bcol]     = *(const float4*)(xb + (size_t)(c0 + bk) * N_);
    *(float4*)&Bs[bk + 8][bcol] = *(const float4*)(xb + (size_t)(c0 + bk + 8) * N_);
    __syncthreads();
#pragma unroll
    for (int k = 0; k < 16; ++k) {
      float a[8], b[8];
      *(float4*)&a[0] = *(const float4*)&As[k][ty * 4];
      *(float4*)&a[4] = *(const float4*)&As[k][64 + ty * 4];
      *(float4*)&b[0] = *(const float4*)&Bs[k][tx * 4];
      *(float4*)&b[4] = *(const float4*)&Bs[k][64 + tx * 4];
#pragma unroll
      for (int i = 0; i < 8; ++i)
#pragma unroll
        for (int j = 0; j < 8; ++j)
          acc[i][j] = fmaf(a[i], b[j], acc[i][j]);
    }
    __syncthreads();
  }
#pragma unroll
  for (int cg = 0; cg < 2; ++cg) {
    const int jj = j0 + cg * 64 + tx * 4;
    const int tb = jj / N_;
    float* pb = P + (size_t)(g * TB_ + tb) * CN_ + (jj - tb * N_);
#pragma unroll
    for (int rg = 0; rg < 2; ++rg) {
#pragma unroll
      for (int i = 0; i < 4; ++i) {
        const int r = rg * 4 + i;
        const int co = co0 + rg * 64 + ty * 4 + i;
        *(float4*)&pb[(size_t)co * N_] = make_float4(
            acc[r][cg * 4 + 0], acc[r][cg * 4 + 1],
            acc[r][cg * 4 + 2], acc[r][cg * 4 + 3]);
      }
    }
  }
}

// ---------------------------------------------------------------------------
// Multi-step LIF over t with folded BN (final conv only).
// ---------------------------------------------------------------------------
__global__ __launch_bounds__(256) void lif4(
    const float* __restrict__ In, float* __restrict__ Out,
    const float* __restrict__ s0, const float* __restrict__ b0, float vth)
{
  const long u = (long)blockIdx.x * 256 + threadIdx.x;
  if (u >= BCN4_) return;
  const long r = u;
  const int c = (int)((r / (N_ / 4)) % C_);
  const bool has_bn = (s0 != nullptr);
  const float sc = has_bn ? s0[c] : 1.0f;
  const float bi = has_bn ? b0[c] : 0.0f;
  const float4* In4 = (const float4*)In;
  float4* Out4 = (float4*)Out;
  float v[4] = {0.f, 0.f, 0.f, 0.f};
#pragma unroll
  for (int t = 0; t < T_; ++t) {
    const long idx = (long)t * BCN4_ + r;
    const float4 y4 = In4[idx];
    float y[4] = {y4.x, y4.y, y4.z, y4.w};
    float o[4];
#pragma unroll
    for (int e = 0; e < 4; ++e) {
      const float yb = has_bn ? __fadd_rn(__fmul_rn(y[e], sc), bi) : y[e];
      v[e] = __fadd_rn(v[e], __fmul_rn(__fsub_rn(yb, v[e]), 0.5f));
      const bool fire = (v[e] >= vth);
      o[e] = fire ? 1.0f : 0.0f;
      v[e] = fire ? 0.0f : v[e];
    }
    Out4[idx] = make_float4(o[0], o[1], o[2], o[3]);
  }
}

// ---------------------------------------------------------------------------
// k_mask: conv-LIF -> spike bitmasks. Wave-task = (g,h,b,j): 16 loads in
// flight (4 words x 4 t), LIF recurrence, 16 ballots, lane0 stores 16 u64.
// MSK layout: [(h*32+b)][g][t][j][w]  (2304 u64 per (h,b)).
// ---------------------------------------------------------------------------
__global__ __launch_bounds__(256) void k_mask(
    const float* __restrict__ P, u64* __restrict__ MSK,
    const float* __restrict__ sq, const float* __restrict__ bq,
    const float* __restrict__ sk, const float* __restrict__ bk,
    const float* __restrict__ sv, const float* __restrict__ bv)
{
  const int wave = threadIdx.x >> 6, lane = threadIdx.x & 63;
  const int task = blockIdx.x * 4 + wave;      // 0..36863
  const int j = task % D_;
  int r = task / D_;
  const int b = r & 31; r >>= 5;
  const int h = r & 7;  r >>= 3;
  const int g = r;                              // 0..2
  const int c = h * D_ + j;
  const float sc = (g == 0 ? sq : g == 1 ? sk : sv)[c];
  const float bi = (g == 0 ? bq : g == 1 ? bk : bv)[c];
  const float* base = P + (size_t)g * TB_ * CN_ + (size_t)b * CN_ + (size_t)c * N_;

  float y[4][T_];
  bool act[4];
#pragma unroll
  for (int w = 0; w < 4; ++w) {
    const int m = w * 64 + lane;
    act[w] = (m < N_);
    const int mc = act[w] ? m : (N_ - 1);
#pragma unroll
    for (int t = 0; t < T_; ++t)
      y[w][t] = base[(size_t)t * B_ * CN_ + mc];   // 16 independent loads
  }
  u64* mb = MSK + ((size_t)(h * 32 + b) * 3 + g) * (T_ * D_ * 4) + j * 4;
  float v[4] = {0.f, 0.f, 0.f, 0.f};
#pragma unroll
  for (int t = 0; t < T_; ++t) {
#pragma unroll
    for (int w = 0; w < 4; ++w) {
      const float yb = __fadd_rn(__fmul_rn(y[w][t], sc), bi);
      v[w] = __fadd_rn(v[w], __fmul_rn(__fsub_rn(yb, v[w]), 0.5f));
      const bool fire = (v[w] >= 1.0f);
      if (fire) v[w] = 0.f;
      const u64 bl = __ballot(fire && act[w]);
      if (lane == 0) mb[(size_t)t * (D_ * 4) + w] = bl;
    }
  }
}

// ---------------------------------------------------------------------------
// k_attn: per (h,b): load 18 KB of masks to LDS, build qT + G bit-planes,
// apply out = sum_p 2^p popcount(qT & Gp[p][d]), attn-LIF, write spikes.
// ---------------------------------------------------------------------------
__global__ __launch_bounds__(1024) void k_attn(
    const u64* __restrict__ MSK, float* __restrict__ O)
{
  const int h = blockIdx.x;   // 8
  const int b = blockIdx.y;   // 32
  __shared__ u64 msk[3][T_][D_][4];   // 18432 B
  __shared__ u64 qT[T_][208];         // 6656 B
  __shared__ u64 Gp[T_][8][D_];       // 12288 B
  const int tid = threadIdx.x;
  const int wave = tid >> 6, lane = tid & 63;

  {
    const u64* ms = MSK + (size_t)(h * 32 + b) * 2304;
    u64* mf = &msk[0][0][0][0];
    for (int off = tid; off < 2304; off += 1024) mf[off] = ms[off];
  }
  __syncthreads();

  // qT[t][n] = q bits over j
  {
    const int t = wave >> 2, w = wave & 3;
    const int n = w * 64 + lane;
    u64 qr = 0ull;
#pragma unroll 8
    for (int j = 0; j < D_; ++j)
      qr |= ((msk[0][t][j][w] >> lane) & 1ull) << j;
    if (n < N_) qT[t][n] = qr;
  }
  // Gp[t][p][d]: bit-planes of G[j][d] = popcount_m(k_j & v_d), lanes=j
  for (int task = wave; task < T_ * D_; task += 16) {
    const int t = task / D_, d = task - (task / D_) * D_;
    const bool ja = (lane < D_);
    const int j = ja ? lane : (D_ - 1);
    const u64* kj = msk[1][t][j];
    const u64* vd = msk[2][t][d];
    const int gi = __popcll(kj[0] & vd[0]) + __popcll(kj[1] & vd[1]) +
                   __popcll(kj[2] & vd[2]) + __popcll(kj[3] & vd[3]);
#pragma unroll
    for (int p = 0; p < 8; ++p) {
      const u64 bl = __ballot(ja && ((gi >> p) & 1));
      if (lane == 0) Gp[t][p][d] = bl;
    }
  }
  __syncthreads();

  const int u = tid;
  if (u < 4 * N_) {
    const int dq = u / N_;
    const int n = u - dq * N_;
    const int d0 = dq * 12;
    float vmem[12];
#pragma unroll
    for (int i = 0; i < 12; ++i) vmem[i] = 0.f;
    for (int t = 0; t < T_; ++t) {
      const u64 qr = qT[t][n];
      float* ob = O + ((size_t)(t * B_ + b) * C_ + h * D_ + d0) * N_ + n;
#pragma unroll
      for (int i = 0; i < 12; ++i) {
        int acc = 0;
#pragma unroll
        for (int p = 0; p < 8; ++p)
          acc += __popcll(qr & Gp[t][p][d0 + i]) << p;
        const float y = __int2float_rn(acc) * 0.125f;  // exact
        vmem[i] = __fadd_rn(vmem[i], __fmul_rn(__fsub_rn(y, vmem[i]), 0.5f));
        const bool fire = (vmem[i] >= 0.5f);
        ob[(size_t)i * N_] = fire ? 1.0f : 0.0f;
        if (fire) vmem[i] = 0.f;
      }
    }
  }
}

// ---------------------------------------------------------------------------
extern "C" void kernel_launch(void* const* d_in, const int* in_sizes, int n_in,
                              void* d_out, int out_size, void* d_ws, size_t ws_size,
                              hipStream_t stream) {
  const float* x  = (const float*)d_in[0];
  const float* wq = (const float*)d_in[1];
  const float* sq = (const float*)d_in[2];
  const float* bq = (const float*)d_in[3];
  const float* wk = (const float*)d_in[4];
  const float* sk = (const float*)d_in[5];
  const float* bk = (const float*)d_in[6];
  const float* wv = (const float*)d_in[7];
  const float* sv = (const float*)d_in[8];
  const float* bv = (const float*)d_in[9];
  const float* wp = (const float*)d_in[10];
  const float* sp = (const float*)d_in[11];
  const float* bp = (const float*)d_in[12];
  float* out = (float*)d_out;

  float* P = (float*)d_ws;              // 3*TBCN qkv preacts
  float* O = P + 3 * TBCN_;             // TBCN attn spikes
  u64* MSK = (u64*)(P + 4 * TBCN_);     // 256 * 2304 u64 = 4.7 MB
  float* P2 = P;                        // final conv preact reuses q region

  gemm_f32<<<dim3(196, 3, 3), 256, 0, stream>>>(x, wq, wk, wv, P);
  k_mask<<<dim3(9216), 256, 0, stream>>>(P, MSK, sq, bq, sk, bk, sv, bv);
  k_attn<<<dim3(NH_, B_), 1024, 0, stream>>>(MSK, O);
  gemm_f32<<<dim3(196, 3, 1), 256, 0, stream>>>(O, wp, wp, wp, P2);
  lif4<<<dim3((BCN4_ + 255) / 256), 256, 0, stream>>>(P2, out, sp, bp, 1.0f);
}